// Round 17
// baseline (1812.149 us; speedup 1.0000x reference)
//
#include <hip/hip_runtime.h>
#include <hip/hip_bf16.h>

#define HS 64
#define NH 16
#define DMODEL 1024
#define SEQ 1024
#define NB 4
#define NL 6
#define VOCAB 32000
#define EPS_LN 1e-5f

static constexpr int ROWS = NB * SEQ;  // 4096

typedef float f32x4 __attribute__((ext_vector_type(4)));
typedef short bf16x8 __attribute__((ext_vector_type(8)));
typedef unsigned short u16x8 __attribute__((ext_vector_type(8)));
typedef unsigned short u16x4 __attribute__((ext_vector_type(4)));

__device__ __forceinline__ unsigned short f2b(float f) {
  __hip_bfloat16 h = __float2bfloat16(f);
  return *reinterpret_cast<unsigned short*>(&h);
}
__device__ __forceinline__ void gload_lds16(const void* g, void* l) {
  __builtin_amdgcn_global_load_lds(
      (const __attribute__((address_space(1))) void*)g,
      (__attribute__((address_space(3))) void*)l, 16, 0, 0);
}
#define MFMA16 __builtin_amdgcn_mfma_f32_16x16x32_bf16
#define EXP2F __builtin_amdgcn_exp2f

// ---------------- embedding ----------------
__global__ __launch_bounds__(256) void embed_kernel(
    const int* __restrict__ tokens, const float* __restrict__ tok_emb,
    const float* __restrict__ pos_emb, float* __restrict__ x) {
  int row = blockIdx.x;
  int t = row & (SEQ - 1);
  int tok = tokens[row];
  int d = threadIdx.x * 4;
  float4 te = *(const float4*)(tok_emb + (size_t)tok * DMODEL + d);
  float4 pe = *(const float4*)(pos_emb + (size_t)t * DMODEL + d);
  te.x += pe.x; te.y += pe.y; te.z += pe.z; te.w += pe.w;
  *(float4*)(x + (size_t)row * DMODEL + d) = te;
}

// ---------------- LayerNorm: f32 in -> bf16 out ----------------
__global__ __launch_bounds__(256) void ln_kernel(
    const float* __restrict__ in, unsigned short* __restrict__ outp,
    const float* __restrict__ g, const float* __restrict__ b) {
  int row = blockIdx.x;
  int tid = threadIdx.x;
  const float* xr = in + (size_t)row * DMODEL;
  float4 v4 = *(const float4*)(xr + tid * 4);
  float s = v4.x + v4.y + v4.z + v4.w;
  float s2 = v4.x * v4.x + v4.y * v4.y + v4.z * v4.z + v4.w * v4.w;
#pragma unroll
  for (int off = 32; off > 0; off >>= 1) {
    s  += __shfl_down(s, off, 64);
    s2 += __shfl_down(s2, off, 64);
  }
  __shared__ float red[8];
  __shared__ float stats[2];
  int wv = tid >> 6, lane = tid & 63;
  if (lane == 0) { red[wv] = s; red[4 + wv] = s2; }
  __syncthreads();
  if (tid == 0) {
    float ts = red[0] + red[1] + red[2] + red[3];
    float ts2 = red[4] + red[5] + red[6] + red[7];
    float mu = ts * (1.0f / DMODEL);
    float var = ts2 * (1.0f / DMODEL) - mu * mu;
    stats[0] = mu;
    stats[1] = rsqrtf(var + EPS_LN);
  }
  __syncthreads();
  float mu = stats[0], rstd = stats[1];
  float4 g4 = *(const float4*)(g + tid * 4);
  float4 b4 = *(const float4*)(b + tid * 4);
  u16x4 o;
  o[0] = f2b((v4.x - mu) * rstd * g4.x + b4.x);
  o[1] = f2b((v4.y - mu) * rstd * g4.y + b4.y);
  o[2] = f2b((v4.z - mu) * rstd * g4.z + b4.z);
  o[3] = f2b((v4.w - mu) * rstd * g4.w + b4.w);
  *(u16x4*)(outp + (size_t)row * DMODEL + tid * 4) = o;
}

// ---------------- transpose-convert: f32 [K][N] -> bf16 [N][K], 64k x 32n tiles ----------------
__global__ __launch_bounds__(256) void transconv(
    const float* __restrict__ in, unsigned short* __restrict__ outp, int K, int N) {
  __shared__ float tile[64][33];
  size_t zoff = (size_t)blockIdx.z * K * N;
  in += zoff;
  outp += zoff;
  int n0 = blockIdx.x * 32, k0 = blockIdx.y * 64;
  int tx = threadIdx.x & 31, ty = threadIdx.x >> 5;
#pragma unroll
  for (int i = 0; i < 8; ++i)
    tile[ty + i * 8][tx] = in[(size_t)(k0 + ty + i * 8) * N + n0 + tx];
  __syncthreads();
  int n = threadIdx.x >> 3;
  int kq = (threadIdx.x & 7) * 8;
  u16x8 o8;
#pragma unroll
  for (int j = 0; j < 8; ++j) o8[j] = f2b(tile[kq + j][n]);
  *(u16x8*)(outp + (size_t)(n0 + n) * K + k0 + kq) = o8;
}

// ---------------- QKV weight transpose-convert (64d x 32s tiles) ----------------
__global__ __launch_bounds__(256) void qkv_transconv(
    const float* __restrict__ Wq, const float* __restrict__ Wk,
    const float* __restrict__ Wv, unsigned short* __restrict__ outp) {
  __shared__ float tile[64][33];
  int z = blockIdx.z;            // l*48 + which*16 + h
  int l = z / 48;
  int r = z % 48;
  int which = r >> 4, h = r & 15;
  const float* W = (which == 0 ? Wq : which == 1 ? Wk : Wv) +
                   ((size_t)l * NH + h) * DMODEL * HS;
  int s0 = blockIdx.x * 32, d0 = blockIdx.y * 64;
  int tx = threadIdx.x & 31, ty = threadIdx.x >> 5;
#pragma unroll
  for (int i = 0; i < 8; ++i)
    tile[ty + i * 8][tx] = W[(size_t)(d0 + ty + i * 8) * HS + s0 + tx];
  __syncthreads();
  unsigned short* ob = outp + ((size_t)l * 3072 + which * 1024 + h * 64) * DMODEL;
  int n = threadIdx.x >> 3;
  int kq = (threadIdx.x & 7) * 8;
  u16x8 o8;
#pragma unroll
  for (int j = 0; j < 8; ++j) o8[j] = f2b(tile[kq + j][n]);
  *(u16x8*)(ob + (size_t)(s0 + n) * DMODEL + d0 + kq) = o8;
}

// ---------------- logits GEMM: 256x256 tile, persistent over MSPAN m-tiles ----------------
// grid = (N/256) * 2 blocks; each owns one n-panel, iterates MSPAN m-tiles so the
// 512KB weight panel stays L2/L3-hot across iterations (fetch ~= panel read once).
#define EPI_LOGITS 0
#define EPI_RES 1
#define EPI_RELU 2
#define EPI_QKV 3

template <int MSPAN>
__global__ __launch_bounds__(512, 2) void mmL(
    const unsigned short* __restrict__ A, const unsigned short* __restrict__ Bt,
    const float* __restrict__ bias, float* __restrict__ outf,
    int M, int N, int K) {
  constexpr int BM_ = 256;
  constexpr int NA = 4;
  constexpr int AP = 2;
  constexpr int MFRAG = 8;
  __shared__ __align__(16) unsigned short LDS[2][(BM_ + 256) * 64];
  const int tid = threadIdx.x;
  const int lane = tid & 63, w = tid >> 6;
  const int wm2 = w >> 2, wn4 = w & 3;
  const int l15 = lane & 15, l4 = lane >> 4;

  const int nN = N >> 8;
  int bid = blockIdx.x;
  const int nb = bid >> 1;
  const int mb0 = (bid & 1) * MSPAN;
  const int n0 = nb * 256;

  const int srow = tid >> 3;
  const int scolb = (tid & 7) * 16;
  const int swst = (srow & 7) << 4;
  const char* bS = (const char*)Bt + ((size_t)(n0 + srow) * K) * 2 + (scolb ^ swst);
  const size_t rstep = (size_t)64 * K * 2;

  const int kb0 = l4 * 16;
  const int swz = (l15 & 7) << 4;
  const int NT = K >> 6;
  (void)nN;

#define STAGEX(tt)                                                          \
  {                                                                         \
    unsigned short* ad = &LDS[(tt) & 1][0] + (size_t)tid * 8;               \
    unsigned short* bd = &LDS[(tt) & 1][BM_ * 64] + (size_t)tid * 8;        \
    size_t ko = (size_t)(tt) * 128;                                         \
    _Pragma("unroll")                                                       \
    for (int j = 0; j < NA; ++j) gload_lds16(aS + ko + j * rstep, ad + j * 4096); \
    _Pragma("unroll")                                                       \
    for (int j = 0; j < 4; ++j) gload_lds16(bS + ko + j * rstep, bd + j * 4096);  \
  }

#define READA(dst, p)                                                       \
  _Pragma("unroll")                                                         \
  for (int mm = 0; mm < AP; ++mm)                                           \
  _Pragma("unroll")                                                         \
    for (int ks = 0; ks < 2; ++ks)                                          \
      dst[mm][ks] = *(const bf16x8*)(ab + (AP * (p) + mm) * 2048 +          \
                                     ((kb0 + 64 * ks) ^ swz));

#define GROUP(src, p)                                                       \
  __builtin_amdgcn_s_setprio(1);                                            \
  _Pragma("unroll")                                                         \
  for (int ks = 0; ks < 2; ++ks)                                            \
  _Pragma("unroll")                                                         \
    for (int mm = 0; mm < AP; ++mm)                                         \
    _Pragma("unroll")                                                       \
      for (int ni = 0; ni < 4; ++ni)                                        \
        acc[AP * (p) + mm][ni] =                                            \
            MFMA16(src[mm][ks], bv[ni][ks], acc[AP * (p) + mm][ni], 0, 0, 0);\
  __builtin_amdgcn_s_setprio(0);

  for (int mo = 0; mo < MSPAN; ++mo) {
    const int m0 = (mb0 + mo) * BM_;
    const char* aS = (const char*)A + ((size_t)(m0 + srow) * K) * 2 + (scolb ^ swst);
    f32x4 acc[MFRAG][4] = {};
    bf16x8 bv[4][2], avA[AP][2], avB[AP][2];

    STAGEX(0)
    STAGEX(1)

    for (int t = 0; t < NT; ++t) {
      if (t < NT - 1) asm volatile("s_waitcnt vmcnt(8)" ::: "memory");
      else            asm volatile("s_waitcnt vmcnt(0)" ::: "memory");
      __builtin_amdgcn_s_barrier();
      __builtin_amdgcn_sched_barrier(0);
      const char* ab = (const char*)&LDS[t & 1][0] +
                       (size_t)(wm2 * (BM_ / 2) + l15) * 128;
      const char* bb = (const char*)&LDS[t & 1][BM_ * 64] +
                       (size_t)(wn4 * 64 + l15) * 128;
#pragma unroll
      for (int ni = 0; ni < 4; ++ni)
#pragma unroll
        for (int ks = 0; ks < 2; ++ks)
          bv[ni][ks] = *(const bf16x8*)(bb + ni * 2048 + ((kb0 + 64 * ks) ^ swz));
      READA(avA, 0)
      READA(avB, 1)
      GROUP(avA, 0)
      READA(avA, 2)
      GROUP(avB, 1)
      READA(avB, 3)
      GROUP(avA, 2)
      asm volatile("s_waitcnt lgkmcnt(0)" ::: "memory");
      __builtin_amdgcn_sched_barrier(0);
      __builtin_amdgcn_s_barrier();
      __builtin_amdgcn_sched_barrier(0);
      if (t + 2 < NT) STAGEX(t + 2)
      GROUP(avB, 3)
    }

    // epilogue: stage C through LDS (stride 256), nontemporal row stores
    int cbase = n0 + wn4 * 64 + l15;
    float* fl = (float*)&LDS[0][0];
#pragma unroll
    for (int half = 0; half < 2; ++half) {
      __syncthreads();
      if (wm2 == half) {
#pragma unroll
        for (int ni = 0; ni < 4; ++ni) {
          float bvv = bias[cbase + ni * 16];
          int cl = wn4 * 64 + l15 + ni * 16;
#pragma unroll
          for (int mi = 0; mi < MFRAG; ++mi) {
#pragma unroll
            for (int r = 0; r < 4; ++r) {
              int rl = mi * 16 + (l4 << 2) + r;
              fl[rl * 256 + (cl ^ (((rl >> 2) & 7) << 2))] = acc[mi][ni][r] + bvv;
            }
          }
        }
      }
      __syncthreads();
#pragma unroll
      for (int j = 0; j < 16; ++j) {
        int idx = j * 512 + tid;
        int rl = idx >> 6;
        int cc = (idx & 63) << 2;
        f32x4 v4 = *(const f32x4*)&fl[rl * 256 + (cc ^ (((rl >> 2) & 7) << 2))];
        float* gp = outf + (size_t)(m0 + half * 128 + rl) * N + n0 + cc;
        __builtin_nontemporal_store(v4, (f32x4*)gp);
      }
    }
    __syncthreads();   // fl reads done before next iteration re-stages LDS
  }
#undef STAGEX
#undef READA
#undef GROUP
}

// ---------------- bf16 MFMA GEMM, 128x128 tile (r9 proven), 2 blocks/CU ----------------
template <int EPI>
__global__ __launch_bounds__(256, 2) void mmP(
    const unsigned short* __restrict__ A, const unsigned short* __restrict__ Bt,
    const float* __restrict__ bias, const float* __restrict__ res,
    float* __restrict__ outf, unsigned short* __restrict__ ob0,
    unsigned short* __restrict__ ob1, unsigned short* __restrict__ ob2,
    int M, int N, int K) {
  __shared__ __align__(16) unsigned short LDS[2][16384];
  const int tid = threadIdx.x;
  const int lane = tid & 63, w = tid >> 6;
  const int wm2 = w >> 1, wn2 = w & 1;
  const int l15 = lane & 15, l4 = lane >> 4;

  const int nM = M >> 7, nN = N >> 7;
  const int nwg = nM * nN;
  int bid = blockIdx.x;
  int wg = (bid & 7) * (nwg >> 3) + (bid >> 3);
  int mb = wg % nM, nb = wg / nM;
  const int m0 = mb * 128, n0 = nb * 128;

  const int srow = tid >> 3;
  const int scolb = (tid & 7) * 16;
  const int swst = (srow & 7) << 4;
  const char* aS = (const char*)A + ((size_t)(m0 + srow) * K) * 2 + (scolb ^ swst);
  const char* bS = (const char*)Bt + ((size_t)(n0 + srow) * K) * 2 + (scolb ^ swst);
  const size_t rstep = (size_t)32 * K * 2;

  const int kb0 = l4 * 16;
  const int swz = (l15 & 7) << 4;

  const int NT = K >> 6;
  f32x4 acc[4][4] = {};
  bf16x8 bv[4][2];

#define STAGEX(tt)                                                          \
  {                                                                         \
    unsigned short* ad = &LDS[(tt) & 1][0] + (size_t)tid * 8;               \
    unsigned short* bd = &LDS[(tt) & 1][8192] + (size_t)tid * 8;            \
    size_t ko = (size_t)(tt) * 128;                                         \
    _Pragma("unroll")                                                       \
    for (int j = 0; j < 4; ++j) gload_lds16(aS + ko + j * rstep, ad + j * 2048); \
    _Pragma("unroll")                                                       \
    for (int j = 0; j < 4; ++j) gload_lds16(bS + ko + j * rstep, bd + j * 2048); \
  }

#define RDA(dst, mi)                                                        \
  dst##k0 = *(const bf16x8*)(ab + (mi) * 2048 + (kb0 ^ swz));               \
  dst##k1 = *(const bf16x8*)(ab + (mi) * 2048 + ((kb0 + 64) ^ swz));

#define GROUP(src, mi)                                                      \
  __builtin_amdgcn_s_setprio(1);                                            \
  _Pragma("unroll")                                                         \
  for (int ni = 0; ni < 4; ++ni)                                            \
    acc[mi][ni] = MFMA16(src##k0, bv[ni][0], acc[mi][ni], 0, 0, 0);         \
  _Pragma("unroll")                                                         \
  for (int ni = 0; ni < 4; ++ni)                                            \
    acc[mi][ni] = MFMA16(src##k1, bv[ni][1], acc[mi][ni], 0, 0, 0);         \
  __builtin_amdgcn_s_setprio(0);

  STAGEX(0)
  STAGEX(1)

  for (int t = 0; t < NT; ++t) {
    if (t < NT - 1) asm volatile("s_waitcnt vmcnt(8)" ::: "memory");
    else            asm volatile("s_waitcnt vmcnt(0)" ::: "memory");
    __builtin_amdgcn_s_barrier();
    __builtin_amdgcn_sched_barrier(0);
    const char* ab = (const char*)&LDS[t & 1][0] + (size_t)(wm2 * 64 + l15) * 128;
    const char* bb = (const char*)&LDS[t & 1][8192] + (size_t)(wn2 * 64 + l15) * 128;
    bf16x8 aEk0, aEk1, aOk0, aOk1;
#pragma unroll
    for (int ni = 0; ni < 4; ++ni) {
      bv[ni][0] = *(const bf16x8*)(bb + ni * 2048 + (kb0 ^ swz));
      bv[ni][1] = *(const bf16x8*)(bb + ni * 2048 + ((kb0 + 64) ^ swz));
    }
    RDA(aE, 0)
    GROUP(aE, 0)
    RDA(aO, 1)
    GROUP(aO, 1)
    RDA(aE, 2)
    GROUP(aE, 2)
    RDA(aO, 3)
    asm volatile("s_waitcnt lgkmcnt(0)" ::: "memory");
    __builtin_amdgcn_sched_barrier(0);
    __builtin_amdgcn_s_barrier();
    __builtin_amdgcn_sched_barrier(0);
    if (t + 2 < NT) STAGEX(t + 2)
    GROUP(aO, 3)
  }
#undef STAGEX
#undef RDA
#undef GROUP

  int rbase = m0 + wm2 * 64 + (l4 << 2);
  int cbase = n0 + wn2 * 64 + l15;
#pragma unroll
  for (int ni = 0; ni < 4; ++ni) {
    int col = cbase + ni * 16;
    if (EPI == EPI_QKV) {
      int which = col >> 10;
      int c2 = col & 1023;
      int h = c2 >> 6, s = c2 & 63;
#pragma unroll
      for (int mi = 0; mi < 4; ++mi) {
        f32x4 a4 = acc[mi][ni];
        int row0 = rbase + mi * 16;
        int bb2 = row0 >> 10, t0 = row0 & 1023;
        if (which == 2) {
          u16x4 pk;
          pk[0] = f2b(a4[0]); pk[1] = f2b(a4[1]); pk[2] = f2b(a4[2]); pk[3] = f2b(a4[3]);
          *(u16x4*)(ob2 + ((((size_t)bb2 * NH + h) * HS) + s) * SEQ + t0) = pk;
        } else {
          unsigned short* dst = (which == 0) ? ob0 : ob1;
#pragma unroll
          for (int r = 0; r < 4; ++r)
            dst[((((size_t)bb2 * NH) + h) * SEQ + t0 + r) * HS + s] = f2b(a4[r]);
        }
      }
    } else {
      float bvv = bias[col];
#pragma unroll
      for (int mi = 0; mi < 4; ++mi) {
        f32x4 a4 = acc[mi][ni];
#pragma unroll
        for (int r = 0; r < 4; ++r) {
          int rowg = rbase + mi * 16 + r;
          size_t off = (size_t)rowg * N + col;
          float v = a4[r] + bvv;
          if (EPI == EPI_RES) outf[off] = v + res[off];
          else if (EPI == EPI_RELU) ob0[off] = f2b(fmaxf(v, 0.f));
        }
      }
    }
  }
}

// ---------------- MFMA flash attention (QBLK=128, KVBLK=128, 8 waves, dbuf) ----------------
__global__ __launch_bounds__(512) void attn_mfma(
    const unsigned short* __restrict__ q, const unsigned short* __restrict__ k,
    const unsigned short* __restrict__ vt, unsigned short* __restrict__ outp) {
  __shared__ __align__(16) unsigned short S[32768];  // K[2][8192] | V[2][8192] = 64KB
  unsigned short* Ks = S;
  unsigned short* Vs = S + 16384;
  int qt = blockIdx.x, bh = blockIdx.y;
  int tid = threadIdx.x;
  int lane = tid & 63, w = tid >> 6;
  int l15 = lane & 15, l4 = lane >> 4;

  const unsigned short* qb = q + (size_t)bh * SEQ * HS;
  const unsigned short* kb = k + (size_t)bh * SEQ * HS;
  const unsigned short* vb = vt + (size_t)bh * HS * SEQ;

  int q_l = w * 16 + l15;
  int q_g = qt * 128 + q_l;
  bf16x8 qf[2];
  qf[0] = *(const bf16x8*)(qb + (size_t)q_g * HS + l4 * 8);
  qf[1] = *(const bf16x8*)(qb + (size_t)q_g * HS + l4 * 8 + 32);

  int kOff[2], vOff[2];
#pragma unroll
  for (int j = 0; j < 2; ++j) {
    int idx = tid + j * 512;
    kOff[j] = (idx >> 7) * 16 * HS + (idx & 15) * HS + ((idx >> 4) & 7) * 8;
    vOff[j] = ((idx >> 8) * 16 + (idx & 15)) * SEQ + ((idx >> 4) & 15) * 8;
  }

#define ASTAGE(tt)                                                           \
  {                                                                          \
    int bsel = ((tt) & 1) * 8192;                                            \
    const unsigned short* ksrc = kb + (size_t)(tt) * 128 * HS;               \
    const unsigned short* vsrc = vb + (tt) * 128;                            \
    _Pragma("unroll")                                                        \
    for (int j = 0; j < 2; ++j)                                              \
      gload_lds16(ksrc + kOff[j], Ks + bsel + (size_t)(tid + j * 512) * 8);  \
    _Pragma("unroll")                                                        \
    for (int j = 0; j < 2; ++j)                                              \
      gload_lds16(vsrc + vOff[j], Vs + bsel + (size_t)(tid + j * 512) * 8);  \
  }

  f32x4 o[4] = {};
  float mrun = -3e38f, lrun = 0.f;
  int baseLane = 32 * (l4 & 1) + l15;
  bool hi_t = (l4 >> 1) != 0;
  const float CSC = 0.125f * 1.44269504f;
  const float THR = 8.0f / CSC;

  int nt2 = qt + 1;
  ASTAGE(0)

  for (int kt = 0; kt < nt2; ++kt) {
    asm volatile("s_waitcnt vmcnt(0)" ::: "memory");
    __builtin_amdgcn_s_barrier();
    __builtin_amdgcn_sched_barrier(0);
    if (kt + 1 < nt2) ASTAGE(kt + 1)
    const unsigned short* Kb = Ks + (kt & 1) * 8192;
    const unsigned short* Vb = Vs + (kt & 1) * 8192;

    f32x4 s[8];
    __builtin_amdgcn_s_setprio(1);
#pragma unroll
    for (int t = 0; t < 8; ++t) {
      bf16x8 kf0 = *(const bf16x8*)(Kb + ((size_t)(t * 8 + l4) * 16 + l15) * 8);
      bf16x8 kf1 = *(const bf16x8*)(Kb + ((size_t)(t * 8 + l4 + 4) * 16 + l15) * 8);
      s[t] = (f32x4){0.f, 0.f, 0.f, 0.f};
      s[t] = MFMA16(kf0, qf[0], s[t], 0, 0, 0);
      s[t] = MFMA16(kf1, qf[1], s[t], 0, 0, 0);
    }
    __builtin_amdgcn_s_setprio(0);

    if (kt == nt2 - 1) {
      int keybase = kt * 128 + 4 * l4;
#pragma unroll
      for (int t = 0; t < 8; ++t)
#pragma unroll
        for (int r = 0; r < 4; ++r)
          if (keybase + 16 * t + r > q_g) s[t][r] = -3e38f;
    }
    float mx = -3e38f;
#pragma unroll
    for (int t = 0; t < 8; ++t)
#pragma unroll
      for (int r = 0; r < 4; ++r) mx = fmaxf(mx, s[t][r]);
    mx = fmaxf(mx, __shfl_xor(mx, 16, 64));
    mx = fmaxf(mx, __shfl_xor(mx, 32, 64));
    if (!__all(mx - mrun <= THR)) {
      float mnew = fmaxf(mrun, mx);
      float sc = EXP2F((mrun - mnew) * CSC);
      lrun *= sc;
#pragma unroll
      for (int t2 = 0; t2 < 4; ++t2)
#pragma unroll
        for (int r = 0; r < 4; ++r) o[t2][r] *= sc;
      mrun = mnew;
    }
    float mc = mrun * CSC;
    float ps = 0.f;
#pragma unroll
    for (int t = 0; t < 8; ++t)
#pragma unroll
      for (int r = 0; r < 4; ++r) {
        float e = EXP2F(__builtin_fmaf(s[t][r], CSC, -mc));
        s[t][r] = e;
        ps += e;
      }
    ps += __shfl_xor(ps, 16, 64);
    ps += __shfl_xor(ps, 32, 64);
    lrun += ps;

    int pd[8][2];
#pragma unroll
    for (int t = 0; t < 8; ++t)
#pragma unroll
      for (int h = 0; h < 2; ++h)
        pd[t][h] = (int)f2b(s[t][2 * h]) | ((int)f2b(s[t][2 * h + 1]) << 16);

#pragma unroll
    for (int kk = 0; kk < 4; ++kk) {
      int a0 = __shfl(pd[2 * kk][0], baseLane, 64);
      int b0 = __shfl(pd[2 * kk + 1][0], baseLane, 64);
      int a1 = __shfl(pd[2 * kk][1], baseLane, 64);
      int b1 = __shfl(pd[2 * kk + 1][1], baseLane, 64);
      int a2 = __shfl(pd[2 * kk][0], baseLane + 16, 64);
      int b2 = __shfl(pd[2 * kk + 1][0], baseLane + 16, 64);
      int a3 = __shfl(pd[2 * kk][1], baseLane + 16, 64);
      int b3 = __shfl(pd[2 * kk + 1][1], baseLane + 16, 64);
      union { int4 i4; bf16x8 v; } yu;
      yu.i4.x = hi_t ? b0 : a0;
      yu.i4.y = hi_t ? b1 : a1;
      yu.i4.z = hi_t ? b2 : a2;
      yu.i4.w = hi_t ? b3 : a3;
      __builtin_amdgcn_s_setprio(1);
#pragma unroll
      for (int t2 = 0; t2 < 4; ++t2) {
        bf16x8 vf = *(const bf16x8*)(Vb + ((size_t)(t2 * 16 + kk * 4 + l4) * 16 + l15) * 8);
        o[t2] = MFMA16(vf, yu.v, o[t2], 0, 0, 0);
      }
      __builtin_amdgcn_s_setprio(0);
    }
  }
#undef ASTAGE

  __syncthreads();
  float inv = 1.0f / lrun;
  unsigned short* Ol = S;
#pragma unroll
  for (int t2 = 0; t2 < 4; ++t2) {
    u16x4 p4;
#pragma unroll
    for (int r = 0; r < 4; ++r) p4[r] = f2b(o[t2][r] * inv);
    *(u16x4*)(Ol + (size_t)q_l * 72 + 16 * t2 + 4 * l4) = p4;
  }
  __syncthreads();
  int row = tid >> 2, hs0 = (tid & 3) * 16;
  int bidx = bh >> 4, h = bh & 15;
  size_t gbase = ((size_t)bidx * SEQ + qt * 128 + row) * DMODEL + h * HS + hs0;
  u16x8 r0 = *(const u16x8*)(Ol + (size_t)row * 72 + hs0);
  u16x8 r1 = *(const u16x8*)(Ol + (size_t)row * 72 + hs0 + 8);
  *(u16x8*)(outp + gbase) = r0;
  *(u16x8*)(outp + gbase + 8) = r1;
}

extern "C" void kernel_launch(void* const* d_in, const int* in_sizes, int n_in,
                              void* d_out, int out_size, void* d_ws, size_t ws_size,
                              hipStream_t stream) {
  const int*   tokens  = (const int*)d_in[0];
  const float* tok_emb = (const float*)d_in[1];
  const float* pos_emb = (const float*)d_in[2];
  const float* Wq      = (const float*)d_in[3];
  const float* Wk      = (const float*)d_in[4];
  const float* Wv      = (const float*)d_in[5];
  const float* Wo      = (const float*)d_in[6];
  const float* bo      = (const float*)d_in[7];
  const float* ln1_g   = (const float*)d_in[8];
  const float* ln1_b   = (const float*)d_in[9];
  const float* ln2_g   = (const float*)d_in[10];
  const float* ln2_b   = (const float*)d_in[11];
  const float* W1      = (const float*)d_in[12];
  const float* b1      = (const float*)d_in[13];
  const float* W2      = (const float*)d_in[14];
  const float* b2      = (const float*)d_in[15];
  const float* lnf_g   = (const float*)d_in[16];
  const float* lnf_b   = (const float*)d_in[17];
  const float* W_out   = (const float*)d_in[18];
  const float* b_out   = (const float*)d_in[19];
  float* logits = (float*)d_out;

  char* p = (char*)d_ws;
  float* x = (float*)p;            p += (size_t)ROWS * DMODEL * 4;
  unsigned short* hb = (unsigned short*)p;  p += (size_t)ROWS * DMODEL * 2;
  unsigned short* qb = (unsigned short*)p;  p += (size_t)ROWS * DMODEL * 2;
  unsigned short* kb = (unsigned short*)p;  p += (size_t)ROWS * DMODEL * 2;
  unsigned short* vtb = (unsigned short*)p; p += (size_t)ROWS * DMODEL * 2;
  unsigned short* att = (unsigned short*)p; p += (size_t)ROWS * DMODEL * 2;
  unsigned short* hid = (unsigned short*)p; p += (size_t)ROWS * 4 * DMODEL * 2;
  unsigned short* qkvt = (unsigned short*)p; p += (size_t)NL * 3 * DMODEL * DMODEL * 2;
  unsigned short* wot = (unsigned short*)p;  p += (size_t)NL * DMODEL * DMODEL * 2;
  unsigned short* w1t = (unsigned short*)p;  p += (size_t)NL * 4 * DMODEL * DMODEL * 2;
  unsigned short* w2t = (unsigned short*)p;  p += (size_t)NL * 4 * DMODEL * DMODEL * 2;
  unsigned short* woutt = (unsigned short*)p; p += (size_t)VOCAB * DMODEL * 2;

  transconv<<<dim3(32, 16, NL), 256, 0, stream>>>(Wo, wot, DMODEL, DMODEL);
  transconv<<<dim3(128, 16, NL), 256, 0, stream>>>(W1, w1t, DMODEL, 4 * DMODEL);
  transconv<<<dim3(32, 64, NL), 256, 0, stream>>>(W2, w2t, 4 * DMODEL, DMODEL);
  transconv<<<dim3(1000, 16, 1), 256, 0, stream>>>(W_out, woutt, DMODEL, VOCAB);
  qkv_transconv<<<dim3(2, 16, NL * 48), 256, 0, stream>>>(Wq, Wk, Wv, qkvt);

  embed_kernel<<<ROWS, 256, 0, stream>>>(tokens, tok_emb, pos_emb, x);

  for (int l = 0; l < NL; ++l) {
    ln_kernel<<<ROWS, 256, 0, stream>>>(x, hb, ln1_g + l * DMODEL, ln1_b + l * DMODEL);
    mmP<EPI_QKV><<<768, 256, 0, stream>>>(
        hb, qkvt + (size_t)l * 3 * DMODEL * DMODEL, nullptr, nullptr,
        nullptr, qb, kb, vtb, ROWS, 3 * DMODEL, DMODEL);
    attn_mfma<<<dim3(SEQ / 128, NB * NH), 512, 0, stream>>>(qb, kb, vtb, att);
    mmP<EPI_RES><<<256, 256, 0, stream>>>(
        att, wot + (size_t)l * DMODEL * DMODEL, bo + l * DMODEL, x,
        x, nullptr, nullptr, nullptr, ROWS, DMODEL, DMODEL);
    ln_kernel<<<ROWS, 256, 0, stream>>>(x, hb, ln2_g + l * DMODEL, ln2_b + l * DMODEL);
    mmP<EPI_RELU><<<1024, 256, 0, stream>>>(
        hb, w1t + (size_t)l * 4 * DMODEL * DMODEL, b1 + (size_t)l * 4 * DMODEL, nullptr,
        nullptr, hid, nullptr, nullptr, ROWS, 4 * DMODEL, DMODEL);
    mmP<EPI_RES><<<256, 256, 0, stream>>>(
        hid, w2t + (size_t)l * 4 * DMODEL * DMODEL, b2 + l * DMODEL, x,
        x, nullptr, nullptr, nullptr, ROWS, DMODEL, 4 * DMODEL);
  }

  ln_kernel<<<ROWS, 256, 0, stream>>>(x, hb, lnf_g, lnf_b);
  mmL<8><<<250, 512, 0, stream>>>(hb, woutt, b_out, logits, ROWS, VOCAB, DMODEL);
}

// Round 18
// 1714.045 us; speedup vs baseline: 1.0572x; 1.0572x over previous
//
#include <hip/hip_runtime.h>
#include <hip/hip_bf16.h>

#define HS 64
#define NH 16
#define DMODEL 1024
#define SEQ 1024
#define NB 4
#define NL 6
#define VOCAB 32000
#define EPS_LN 1e-5f

static constexpr int ROWS = NB * SEQ;  // 4096

typedef float f32x4 __attribute__((ext_vector_type(4)));
typedef short bf16x8 __attribute__((ext_vector_type(8)));
typedef unsigned short u16x8 __attribute__((ext_vector_type(8)));
typedef unsigned short u16x4 __attribute__((ext_vector_type(4)));

__device__ __forceinline__ unsigned short f2b(float f) {
  __hip_bfloat16 h = __float2bfloat16(f);
  return *reinterpret_cast<unsigned short*>(&h);
}
__device__ __forceinline__ void gload_lds16(const void* g, void* l) {
  __builtin_amdgcn_global_load_lds(
      (const __attribute__((address_space(1))) void*)g,
      (__attribute__((address_space(3))) void*)l, 16, 0, 0);
}
#define MFMA16 __builtin_amdgcn_mfma_f32_16x16x32_bf16
#define EXP2F __builtin_amdgcn_exp2f

// ---------------- embedding ----------------
__global__ __launch_bounds__(256) void embed_kernel(
    const int* __restrict__ tokens, const float* __restrict__ tok_emb,
    const float* __restrict__ pos_emb, float* __restrict__ x) {
  int row = blockIdx.x;
  int t = row & (SEQ - 1);
  int tok = tokens[row];
  int d = threadIdx.x * 4;
  float4 te = *(const float4*)(tok_emb + (size_t)tok * DMODEL + d);
  float4 pe = *(const float4*)(pos_emb + (size_t)t * DMODEL + d);
  te.x += pe.x; te.y += pe.y; te.z += pe.z; te.w += pe.w;
  *(float4*)(x + (size_t)row * DMODEL + d) = te;
}

// ---------------- LayerNorm: f32 in -> bf16 out ----------------
__global__ __launch_bounds__(256) void ln_kernel(
    const float* __restrict__ in, unsigned short* __restrict__ outp,
    const float* __restrict__ g, const float* __restrict__ b) {
  int row = blockIdx.x;
  int tid = threadIdx.x;
  const float* xr = in + (size_t)row * DMODEL;
  float4 v4 = *(const float4*)(xr + tid * 4);
  float s = v4.x + v4.y + v4.z + v4.w;
  float s2 = v4.x * v4.x + v4.y * v4.y + v4.z * v4.z + v4.w * v4.w;
#pragma unroll
  for (int off = 32; off > 0; off >>= 1) {
    s  += __shfl_down(s, off, 64);
    s2 += __shfl_down(s2, off, 64);
  }
  __shared__ float red[8];
  __shared__ float stats[2];
  int wv = tid >> 6, lane = tid & 63;
  if (lane == 0) { red[wv] = s; red[4 + wv] = s2; }
  __syncthreads();
  if (tid == 0) {
    float ts = red[0] + red[1] + red[2] + red[3];
    float ts2 = red[4] + red[5] + red[6] + red[7];
    float mu = ts * (1.0f / DMODEL);
    float var = ts2 * (1.0f / DMODEL) - mu * mu;
    stats[0] = mu;
    stats[1] = rsqrtf(var + EPS_LN);
  }
  __syncthreads();
  float mu = stats[0], rstd = stats[1];
  float4 g4 = *(const float4*)(g + tid * 4);
  float4 b4 = *(const float4*)(b + tid * 4);
  u16x4 o;
  o[0] = f2b((v4.x - mu) * rstd * g4.x + b4.x);
  o[1] = f2b((v4.y - mu) * rstd * g4.y + b4.y);
  o[2] = f2b((v4.z - mu) * rstd * g4.z + b4.z);
  o[3] = f2b((v4.w - mu) * rstd * g4.w + b4.w);
  *(u16x4*)(outp + (size_t)row * DMODEL + tid * 4) = o;
}

// ---------------- transpose-convert: f32 [K][N] -> bf16 [N][K], 64k x 32n tiles ----------------
__global__ __launch_bounds__(256) void transconv(
    const float* __restrict__ in, unsigned short* __restrict__ outp, int K, int N) {
  __shared__ float tile[64][33];
  size_t zoff = (size_t)blockIdx.z * K * N;
  in += zoff;
  outp += zoff;
  int n0 = blockIdx.x * 32, k0 = blockIdx.y * 64;
  int tx = threadIdx.x & 31, ty = threadIdx.x >> 5;
#pragma unroll
  for (int i = 0; i < 8; ++i)
    tile[ty + i * 8][tx] = in[(size_t)(k0 + ty + i * 8) * N + n0 + tx];
  __syncthreads();
  int n = threadIdx.x >> 3;
  int kq = (threadIdx.x & 7) * 8;
  u16x8 o8;
#pragma unroll
  for (int j = 0; j < 8; ++j) o8[j] = f2b(tile[kq + j][n]);
  *(u16x8*)(outp + (size_t)(n0 + n) * K + k0 + kq) = o8;
}

// ---------------- QKV weight transpose-convert (64d x 32s tiles) ----------------
__global__ __launch_bounds__(256) void qkv_transconv(
    const float* __restrict__ Wq, const float* __restrict__ Wk,
    const float* __restrict__ Wv, unsigned short* __restrict__ outp) {
  __shared__ float tile[64][33];
  int z = blockIdx.z;            // l*48 + which*16 + h
  int l = z / 48;
  int r = z % 48;
  int which = r >> 4, h = r & 15;
  const float* W = (which == 0 ? Wq : which == 1 ? Wk : Wv) +
                   ((size_t)l * NH + h) * DMODEL * HS;
  int s0 = blockIdx.x * 32, d0 = blockIdx.y * 64;
  int tx = threadIdx.x & 31, ty = threadIdx.x >> 5;
#pragma unroll
  for (int i = 0; i < 8; ++i)
    tile[ty + i * 8][tx] = W[(size_t)(d0 + ty + i * 8) * HS + s0 + tx];
  __syncthreads();
  unsigned short* ob = outp + ((size_t)l * 3072 + which * 1024 + h * 64) * DMODEL;
  int n = threadIdx.x >> 3;
  int kq = (threadIdx.x & 7) * 8;
  u16x8 o8;
#pragma unroll
  for (int j = 0; j < 8; ++j) o8[j] = f2b(tile[kq + j][n]);
  *(u16x8*)(ob + (size_t)(s0 + n) * DMODEL + d0 + kq) = o8;
}

// ---------------- bf16 MFMA GEMM, BM_ x 256 tile, BK=64, phase-pipelined (r8 proven) ----------------
// ORDER: 0 = XCD-swizzled m-inner; 1 = XCD-swizzled n-inner (logits best, r14/r15)
#define EPI_LOGITS 0
#define EPI_RES 1
#define EPI_RELU 2
#define EPI_QKV 3

template <int EPI, int BM_, int ORDER>
__global__ __launch_bounds__(512, 2) void mmX(
    const unsigned short* __restrict__ A, const unsigned short* __restrict__ Bt,
    const float* __restrict__ bias, const float* __restrict__ res,
    float* __restrict__ outf, unsigned short* __restrict__ ob0,
    unsigned short* __restrict__ ob1, unsigned short* __restrict__ ob2,
    int M, int N, int K) {
  constexpr int NA = BM_ / 64;
  constexpr int AP = BM_ / 128;
  constexpr int MFRAG = BM_ / 32;
  __shared__ __align__(16) unsigned short LDS[2][(BM_ + 256) * 64];
  const int tid = threadIdx.x;
  const int lane = tid & 63, w = tid >> 6;
  const int wm2 = w >> 2, wn4 = w & 3;
  const int l15 = lane & 15, l4 = lane >> 4;

  const int nM = M / BM_, nN = N >> 8;
  const int nwg = nM * nN;
  int bid = blockIdx.x;
  int wg = (bid & 7) * (nwg >> 3) + (bid >> 3);
  int mb, nb;
  if (ORDER == 1) { nb = wg % nN; mb = wg / nN; }
  else            { mb = wg % nM; nb = wg / nM; }
  const int m0 = mb * BM_, n0 = nb * 256;

  const int srow = tid >> 3;
  const int scolb = (tid & 7) * 16;
  const int swst = (srow & 7) << 4;
  const char* aS = (const char*)A + ((size_t)(m0 + srow) * K) * 2 + (scolb ^ swst);
  const char* bS = (const char*)Bt + ((size_t)(n0 + srow) * K) * 2 + (scolb ^ swst);
  const size_t rstep = (size_t)64 * K * 2;

  const int kb0 = l4 * 16;
  const int swz = (l15 & 7) << 4;

  const int NT = K >> 6;
  f32x4 acc[MFRAG][4] = {};
  bf16x8 bv[4][2], avA[AP][2], avB[AP][2];

#define STAGEX(tt)                                                          \
  {                                                                         \
    unsigned short* ad = &LDS[(tt) & 1][0] + (size_t)tid * 8;               \
    unsigned short* bd = &LDS[(tt) & 1][BM_ * 64] + (size_t)tid * 8;        \
    size_t ko = (size_t)(tt) * 128;                                         \
    _Pragma("unroll")                                                       \
    for (int j = 0; j < NA; ++j) gload_lds16(aS + ko + j * rstep, ad + j * 4096); \
    _Pragma("unroll")                                                       \
    for (int j = 0; j < 4; ++j) gload_lds16(bS + ko + j * rstep, bd + j * 4096);  \
  }

#define READA(dst, p)                                                       \
  _Pragma("unroll")                                                         \
  for (int mm = 0; mm < AP; ++mm)                                           \
  _Pragma("unroll")                                                         \
    for (int ks = 0; ks < 2; ++ks)                                          \
      dst[mm][ks] = *(const bf16x8*)(ab + (AP * (p) + mm) * 2048 +          \
                                     ((kb0 + 64 * ks) ^ swz));

#define GROUP(src, p)                                                       \
  __builtin_amdgcn_s_setprio(1);                                            \
  _Pragma("unroll")                                                         \
  for (int ks = 0; ks < 2; ++ks)                                            \
  _Pragma("unroll")                                                         \
    for (int mm = 0; mm < AP; ++mm)                                         \
    _Pragma("unroll")                                                       \
      for (int ni = 0; ni < 4; ++ni)                                        \
        acc[AP * (p) + mm][ni] =                                            \
            MFMA16(src[mm][ks], bv[ni][ks], acc[AP * (p) + mm][ni], 0, 0, 0);\
  __builtin_amdgcn_s_setprio(0);

  STAGEX(0)
  STAGEX(1)

  for (int t = 0; t < NT; ++t) {
    if (t < NT - 1) {
      if constexpr (BM_ == 256) asm volatile("s_waitcnt vmcnt(8)" ::: "memory");
      else                      asm volatile("s_waitcnt vmcnt(6)" ::: "memory");
    } else {
      asm volatile("s_waitcnt vmcnt(0)" ::: "memory");
    }
    __builtin_amdgcn_s_barrier();
    __builtin_amdgcn_sched_barrier(0);
    const char* ab = (const char*)&LDS[t & 1][0] +
                     (size_t)(wm2 * (BM_ / 2) + l15) * 128;
    const char* bb = (const char*)&LDS[t & 1][BM_ * 64] +
                     (size_t)(wn4 * 64 + l15) * 128;
#pragma unroll
    for (int ni = 0; ni < 4; ++ni)
#pragma unroll
      for (int ks = 0; ks < 2; ++ks)
        bv[ni][ks] = *(const bf16x8*)(bb + ni * 2048 + ((kb0 + 64 * ks) ^ swz));
    READA(avA, 0)
    READA(avB, 1)
    GROUP(avA, 0)
    READA(avA, 2)
    GROUP(avB, 1)
    READA(avB, 3)
    GROUP(avA, 2)
    asm volatile("s_waitcnt lgkmcnt(0)" ::: "memory");
    __builtin_amdgcn_sched_barrier(0);
    __builtin_amdgcn_s_barrier();
    __builtin_amdgcn_sched_barrier(0);
    if (t + 2 < NT) STAGEX(t + 2)
    GROUP(avB, 3)
  }
#undef STAGEX
#undef READA
#undef GROUP

  int rbase = m0 + wm2 * (BM_ / 2) + (l4 << 2);
  int cbase = n0 + wn4 * 64 + l15;

  if constexpr (EPI == EPI_LOGITS) {
    float* fl = (float*)&LDS[0][0];
#pragma unroll
    for (int half = 0; half < 2; ++half) {
      __syncthreads();
      if (wm2 == half) {
#pragma unroll
        for (int ni = 0; ni < 4; ++ni) {
          float bvv = bias[cbase + ni * 16];
          int cl = wn4 * 64 + l15 + ni * 16;
#pragma unroll
          for (int mi = 0; mi < MFRAG; ++mi) {
#pragma unroll
            for (int r = 0; r < 4; ++r) {
              int rl = mi * 16 + (l4 << 2) + r;
              fl[rl * 256 + (cl ^ (((rl >> 2) & 7) << 2))] = acc[mi][ni][r] + bvv;
            }
          }
        }
      }
      __syncthreads();
#pragma unroll
      for (int j = 0; j < 16; ++j) {
        int idx = j * 512 + tid;
        int rl = idx >> 6;
        int cc = (idx & 63) << 2;
        f32x4 v4 = *(const f32x4*)&fl[rl * 256 + (cc ^ (((rl >> 2) & 7) << 2))];
        float* gp = outf + (size_t)(m0 + half * 128 + rl) * N + n0 + cc;
        __builtin_nontemporal_store(v4, (f32x4*)gp);
      }
    }
  } else {
#pragma unroll
    for (int ni = 0; ni < 4; ++ni) {
      int col = cbase + ni * 16;
      float bvv = 0.f;
      if (EPI != EPI_QKV) bvv = bias[col];
      if (EPI == EPI_QKV) {
        int which = col >> 10;
        int c2 = col & 1023;
        int h = c2 >> 6, s = c2 & 63;
#pragma unroll
        for (int mi = 0; mi < MFRAG; ++mi) {
          f32x4 a4 = acc[mi][ni];
          int row0 = rbase + mi * 16;
          int bb2 = row0 >> 10, t0 = row0 & 1023;
          if (which == 2) {
            u16x4 pk;
            pk[0] = f2b(a4[0]); pk[1] = f2b(a4[1]); pk[2] = f2b(a4[2]); pk[3] = f2b(a4[3]);
            *(u16x4*)(ob2 + ((((size_t)bb2 * NH + h) * HS) + s) * SEQ + t0) = pk;
          } else {
            unsigned short* dst = (which == 0) ? ob0 : ob1;
#pragma unroll
            for (int r = 0; r < 4; ++r)
              dst[((((size_t)bb2 * NH) + h) * SEQ + t0 + r) * HS + s] = f2b(a4[r]);
          }
        }
      } else {
#pragma unroll
        for (int mi = 0; mi < MFRAG; ++mi) {
          f32x4 a4 = acc[mi][ni];
#pragma unroll
          for (int r = 0; r < 4; ++r) {
            int rowg = rbase + mi * 16 + r;
            size_t off = (size_t)rowg * N + col;
            float v = a4[r] + bvv;
            if (EPI == EPI_RES) outf[off] = v + res[off];
            else if (EPI == EPI_RELU) ob0[off] = f2b(fmaxf(v, 0.f));
          }
        }
      }
    }
  }
}

// ---------------- bf16 MFMA GEMM, 128x128 tile (r9 proven), 2 blocks/CU ----------------
template <int EPI>
__global__ __launch_bounds__(256, 2) void mmP(
    const unsigned short* __restrict__ A, const unsigned short* __restrict__ Bt,
    const float* __restrict__ bias, const float* __restrict__ res,
    float* __restrict__ outf, unsigned short* __restrict__ ob0,
    unsigned short* __restrict__ ob1, unsigned short* __restrict__ ob2,
    int M, int N, int K) {
  __shared__ __align__(16) unsigned short LDS[2][16384];
  const int tid = threadIdx.x;
  const int lane = tid & 63, w = tid >> 6;
  const int wm2 = w >> 1, wn2 = w & 1;
  const int l15 = lane & 15, l4 = lane >> 4;

  const int nM = M >> 7, nN = N >> 7;
  const int nwg = nM * nN;
  int bid = blockIdx.x;
  int wg = (bid & 7) * (nwg >> 3) + (bid >> 3);
  int mb = wg % nM, nb = wg / nM;
  const int m0 = mb * 128, n0 = nb * 128;

  const int srow = tid >> 3;
  const int scolb = (tid & 7) * 16;
  const int swst = (srow & 7) << 4;
  const char* aS = (const char*)A + ((size_t)(m0 + srow) * K) * 2 + (scolb ^ swst);
  const char* bS = (const char*)Bt + ((size_t)(n0 + srow) * K) * 2 + (scolb ^ swst);
  const size_t rstep = (size_t)32 * K * 2;

  const int kb0 = l4 * 16;
  const int swz = (l15 & 7) << 4;

  const int NT = K >> 6;
  f32x4 acc[4][4] = {};
  bf16x8 bv[4][2];

#define STAGEX(tt)                                                          \
  {                                                                         \
    unsigned short* ad = &LDS[(tt) & 1][0] + (size_t)tid * 8;               \
    unsigned short* bd = &LDS[(tt) & 1][8192] + (size_t)tid * 8;            \
    size_t ko = (size_t)(tt) * 128;                                         \
    _Pragma("unroll")                                                       \
    for (int j = 0; j < 4; ++j) gload_lds16(aS + ko + j * rstep, ad + j * 2048); \
    _Pragma("unroll")                                                       \
    for (int j = 0; j < 4; ++j) gload_lds16(bS + ko + j * rstep, bd + j * 2048); \
  }

#define RDA(dst, mi)                                                        \
  dst##k0 = *(const bf16x8*)(ab + (mi) * 2048 + (kb0 ^ swz));               \
  dst##k1 = *(const bf16x8*)(ab + (mi) * 2048 + ((kb0 + 64) ^ swz));

#define GROUP(src, mi)                                                      \
  __builtin_amdgcn_s_setprio(1);                                            \
  _Pragma("unroll")                                                         \
  for (int ni = 0; ni < 4; ++ni)                                            \
    acc[mi][ni] = MFMA16(src##k0, bv[ni][0], acc[mi][ni], 0, 0, 0);         \
  _Pragma("unroll")                                                         \
  for (int ni = 0; ni < 4; ++ni)                                            \
    acc[mi][ni] = MFMA16(src##k1, bv[ni][1], acc[mi][ni], 0, 0, 0);         \
  __builtin_amdgcn_s_setprio(0);

  STAGEX(0)
  STAGEX(1)

  for (int t = 0; t < NT; ++t) {
    if (t < NT - 1) asm volatile("s_waitcnt vmcnt(8)" ::: "memory");
    else            asm volatile("s_waitcnt vmcnt(0)" ::: "memory");
    __builtin_amdgcn_s_barrier();
    __builtin_amdgcn_sched_barrier(0);
    const char* ab = (const char*)&LDS[t & 1][0] + (size_t)(wm2 * 64 + l15) * 128;
    const char* bb = (const char*)&LDS[t & 1][8192] + (size_t)(wn2 * 64 + l15) * 128;
    bf16x8 aEk0, aEk1, aOk0, aOk1;
#pragma unroll
    for (int ni = 0; ni < 4; ++ni) {
      bv[ni][0] = *(const bf16x8*)(bb + ni * 2048 + (kb0 ^ swz));
      bv[ni][1] = *(const bf16x8*)(bb + ni * 2048 + ((kb0 + 64) ^ swz));
    }
    RDA(aE, 0)
    GROUP(aE, 0)
    RDA(aO, 1)
    GROUP(aO, 1)
    RDA(aE, 2)
    GROUP(aE, 2)
    RDA(aO, 3)
    asm volatile("s_waitcnt lgkmcnt(0)" ::: "memory");
    __builtin_amdgcn_sched_barrier(0);
    __builtin_amdgcn_s_barrier();
    __builtin_amdgcn_sched_barrier(0);
    if (t + 2 < NT) STAGEX(t + 2)
    GROUP(aO, 3)
  }
#undef STAGEX
#undef RDA
#undef GROUP

  int rbase = m0 + wm2 * 64 + (l4 << 2);
  int cbase = n0 + wn2 * 64 + l15;
#pragma unroll
  for (int ni = 0; ni < 4; ++ni) {
    int col = cbase + ni * 16;
    if (EPI == EPI_QKV) {
      int which = col >> 10;
      int c2 = col & 1023;
      int h = c2 >> 6, s = c2 & 63;
#pragma unroll
      for (int mi = 0; mi < 4; ++mi) {
        f32x4 a4 = acc[mi][ni];
        int row0 = rbase + mi * 16;
        int bb2 = row0 >> 10, t0 = row0 & 1023;
        if (which == 2) {
          u16x4 pk;
          pk[0] = f2b(a4[0]); pk[1] = f2b(a4[1]); pk[2] = f2b(a4[2]); pk[3] = f2b(a4[3]);
          *(u16x4*)(ob2 + ((((size_t)bb2 * NH + h) * HS) + s) * SEQ + t0) = pk;
        } else {
          unsigned short* dst = (which == 0) ? ob0 : ob1;
#pragma unroll
          for (int r = 0; r < 4; ++r)
            dst[((((size_t)bb2 * NH) + h) * SEQ + t0 + r) * HS + s] = f2b(a4[r]);
        }
      }
    } else {
      float bvv = bias[col];
#pragma unroll
      for (int mi = 0; mi < 4; ++mi) {
        f32x4 a4 = acc[mi][ni];
#pragma unroll
        for (int r = 0; r < 4; ++r) {
          int rowg = rbase + mi * 16 + r;
          size_t off = (size_t)rowg * N + col;
          float v = a4[r] + bvv;
          if (EPI == EPI_RES) outf[off] = v + res[off];
          else if (EPI == EPI_RELU) ob0[off] = f2b(fmaxf(v, 0.f));
        }
      }
    }
  }
}

// ---------------- MFMA flash attention (QBLK=128, KVBLK=128, 8 waves, dbuf) ----------------
__global__ __launch_bounds__(512) void attn_mfma(
    const unsigned short* __restrict__ q, const unsigned short* __restrict__ k,
    const unsigned short* __restrict__ vt, unsigned short* __restrict__ outp) {
  __shared__ __align__(16) unsigned short S[32768];  // K[2][8192] | V[2][8192] = 64KB
  unsigned short* Ks = S;
  unsigned short* Vs = S + 16384;
  int qt = blockIdx.x, bh = blockIdx.y;
  int tid = threadIdx.x;
  int lane = tid & 63, w = tid >> 6;
  int l15 = lane & 15, l4 = lane >> 4;

  const unsigned short* qb = q + (size_t)bh * SEQ * HS;
  const unsigned short* kb = k + (size_t)bh * SEQ * HS;
  const unsigned short* vb = vt + (size_t)bh * HS * SEQ;

  int q_l = w * 16 + l15;
  int q_g = qt * 128 + q_l;
  bf16x8 qf[2];
  qf[0] = *(const bf16x8*)(qb + (size_t)q_g * HS + l4 * 8);
  qf[1] = *(const bf16x8*)(qb + (size_t)q_g * HS + l4 * 8 + 32);

  int kOff[2], vOff[2];
#pragma unroll
  for (int j = 0; j < 2; ++j) {
    int idx = tid + j * 512;
    kOff[j] = (idx >> 7) * 16 * HS + (idx & 15) * HS + ((idx >> 4) & 7) * 8;
    vOff[j] = ((idx >> 8) * 16 + (idx & 15)) * SEQ + ((idx >> 4) & 15) * 8;
  }

#define ASTAGE(tt)                                                           \
  {                                                                          \
    int bsel = ((tt) & 1) * 8192;                                            \
    const unsigned short* ksrc = kb + (size_t)(tt) * 128 * HS;               \
    const unsigned short* vsrc = vb + (tt) * 128;                            \
    _Pragma("unroll")                                                        \
    for (int j = 0; j < 2; ++j)                                              \
      gload_lds16(ksrc + kOff[j], Ks + bsel + (size_t)(tid + j * 512) * 8);  \
    _Pragma("unroll")                                                        \
    for (int j = 0; j < 2; ++j)                                              \
      gload_lds16(vsrc + vOff[j], Vs + bsel + (size_t)(tid + j * 512) * 8);  \
  }

  f32x4 o[4] = {};
  float mrun = -3e38f, lrun = 0.f;
  int baseLane = 32 * (l4 & 1) + l15;
  bool hi_t = (l4 >> 1) != 0;
  const float CSC = 0.125f * 1.44269504f;
  const float THR = 8.0f / CSC;

  int nt2 = qt + 1;
  ASTAGE(0)

  for (int kt = 0; kt < nt2; ++kt) {
    asm volatile("s_waitcnt vmcnt(0)" ::: "memory");
    __builtin_amdgcn_s_barrier();
    __builtin_amdgcn_sched_barrier(0);
    if (kt + 1 < nt2) ASTAGE(kt + 1)
    const unsigned short* Kb = Ks + (kt & 1) * 8192;
    const unsigned short* Vb = Vs + (kt & 1) * 8192;

    f32x4 s[8];
    __builtin_amdgcn_s_setprio(1);
#pragma unroll
    for (int t = 0; t < 8; ++t) {
      bf16x8 kf0 = *(const bf16x8*)(Kb + ((size_t)(t * 8 + l4) * 16 + l15) * 8);
      bf16x8 kf1 = *(const bf16x8*)(Kb + ((size_t)(t * 8 + l4 + 4) * 16 + l15) * 8);
      s[t] = (f32x4){0.f, 0.f, 0.f, 0.f};
      s[t] = MFMA16(kf0, qf[0], s[t], 0, 0, 0);
      s[t] = MFMA16(kf1, qf[1], s[t], 0, 0, 0);
    }
    __builtin_amdgcn_s_setprio(0);

    if (kt == nt2 - 1) {
      int keybase = kt * 128 + 4 * l4;
#pragma unroll
      for (int t = 0; t < 8; ++t)
#pragma unroll
        for (int r = 0; r < 4; ++r)
          if (keybase + 16 * t + r > q_g) s[t][r] = -3e38f;
    }
    float mx = -3e38f;
#pragma unroll
    for (int t = 0; t < 8; ++t)
#pragma unroll
      for (int r = 0; r < 4; ++r) mx = fmaxf(mx, s[t][r]);
    mx = fmaxf(mx, __shfl_xor(mx, 16, 64));
    mx = fmaxf(mx, __shfl_xor(mx, 32, 64));
    if (!__all(mx - mrun <= THR)) {
      float mnew = fmaxf(mrun, mx);
      float sc = EXP2F((mrun - mnew) * CSC);
      lrun *= sc;
#pragma unroll
      for (int t2 = 0; t2 < 4; ++t2)
#pragma unroll
        for (int r = 0; r < 4; ++r) o[t2][r] *= sc;
      mrun = mnew;
    }
    float mc = mrun * CSC;
    float ps = 0.f;
#pragma unroll
    for (int t = 0; t < 8; ++t)
#pragma unroll
      for (int r = 0; r < 4; ++r) {
        float e = EXP2F(__builtin_fmaf(s[t][r], CSC, -mc));
        s[t][r] = e;
        ps += e;
      }
    ps += __shfl_xor(ps, 16, 64);
    ps += __shfl_xor(ps, 32, 64);
    lrun += ps;

    int pd[8][2];
#pragma unroll
    for (int t = 0; t < 8; ++t)
#pragma unroll
      for (int h = 0; h < 2; ++h)
        pd[t][h] = (int)f2b(s[t][2 * h]) | ((int)f2b(s[t][2 * h + 1]) << 16);

#pragma unroll
    for (int kk = 0; kk < 4; ++kk) {
      int a0 = __shfl(pd[2 * kk][0], baseLane, 64);
      int b0 = __shfl(pd[2 * kk + 1][0], baseLane, 64);
      int a1 = __shfl(pd[2 * kk][1], baseLane, 64);
      int b1 = __shfl(pd[2 * kk + 1][1], baseLane, 64);
      int a2 = __shfl(pd[2 * kk][0], baseLane + 16, 64);
      int b2 = __shfl(pd[2 * kk + 1][0], baseLane + 16, 64);
      int a3 = __shfl(pd[2 * kk][1], baseLane + 16, 64);
      int b3 = __shfl(pd[2 * kk + 1][1], baseLane + 16, 64);
      union { int4 i4; bf16x8 v; } yu;
      yu.i4.x = hi_t ? b0 : a0;
      yu.i4.y = hi_t ? b1 : a1;
      yu.i4.z = hi_t ? b2 : a2;
      yu.i4.w = hi_t ? b3 : a3;
      __builtin_amdgcn_s_setprio(1);
#pragma unroll
      for (int t2 = 0; t2 < 4; ++t2) {
        bf16x8 vf = *(const bf16x8*)(Vb + ((size_t)(t2 * 16 + kk * 4 + l4) * 16 + l15) * 8);
        o[t2] = MFMA16(vf, yu.v, o[t2], 0, 0, 0);
      }
      __builtin_amdgcn_s_setprio(0);
    }
  }
#undef ASTAGE

  __syncthreads();
  float inv = 1.0f / lrun;
  unsigned short* Ol = S;
#pragma unroll
  for (int t2 = 0; t2 < 4; ++t2) {
    u16x4 p4;
#pragma unroll
    for (int r = 0; r < 4; ++r) p4[r] = f2b(o[t2][r] * inv);
    *(u16x4*)(Ol + (size_t)q_l * 72 + 16 * t2 + 4 * l4) = p4;
  }
  __syncthreads();
  int row = tid >> 2, hs0 = (tid & 3) * 16;
  int bidx = bh >> 4, h = bh & 15;
  size_t gbase = ((size_t)bidx * SEQ + qt * 128 + row) * DMODEL + h * HS + hs0;
  u16x8 r0 = *(const u16x8*)(Ol + (size_t)row * 72 + hs0);
  u16x8 r1 = *(const u16x8*)(Ol + (size_t)row * 72 + hs0 + 8);
  *(u16x8*)(outp + gbase) = r0;
  *(u16x8*)(outp + gbase + 8) = r1;
}

extern "C" void kernel_launch(void* const* d_in, const int* in_sizes, int n_in,
                              void* d_out, int out_size, void* d_ws, size_t ws_size,
                              hipStream_t stream) {
  const int*   tokens  = (const int*)d_in[0];
  const float* tok_emb = (const float*)d_in[1];
  const float* pos_emb = (const float*)d_in[2];
  const float* Wq      = (const float*)d_in[3];
  const float* Wk      = (const float*)d_in[4];
  const float* Wv      = (const float*)d_in[5];
  const float* Wo      = (const float*)d_in[6];
  const float* bo      = (const float*)d_in[7];
  const float* ln1_g   = (const float*)d_in[8];
  const float* ln1_b   = (const float*)d_in[9];
  const float* ln2_g   = (const float*)d_in[10];
  const float* ln2_b   = (const float*)d_in[11];
  const float* W1      = (const float*)d_in[12];
  const float* b1      = (const float*)d_in[13];
  const float* W2      = (const float*)d_in[14];
  const float* b2      = (const float*)d_in[15];
  const float* lnf_g   = (const float*)d_in[16];
  const float* lnf_b   = (const float*)d_in[17];
  const float* W_out   = (const float*)d_in[18];
  const float* b_out   = (const float*)d_in[19];
  float* logits = (float*)d_out;

  char* p = (char*)d_ws;
  float* x = (float*)p;            p += (size_t)ROWS * DMODEL * 4;
  unsigned short* hb = (unsigned short*)p;  p += (size_t)ROWS * DMODEL * 2;
  unsigned short* qb = (unsigned short*)p;  p += (size_t)ROWS * DMODEL * 2;
  unsigned short* kb = (unsigned short*)p;  p += (size_t)ROWS * DMODEL * 2;
  unsigned short* vtb = (unsigned short*)p; p += (size_t)ROWS * DMODEL * 2;
  unsigned short* att = (unsigned short*)p; p += (size_t)ROWS * DMODEL * 2;
  unsigned short* hid = (unsigned short*)p; p += (size_t)ROWS * 4 * DMODEL * 2;
  unsigned short* qkvt = (unsigned short*)p; p += (size_t)NL * 3 * DMODEL * DMODEL * 2;
  unsigned short* wot = (unsigned short*)p;  p += (size_t)NL * DMODEL * DMODEL * 2;
  unsigned short* w1t = (unsigned short*)p;  p += (size_t)NL * 4 * DMODEL * DMODEL * 2;
  unsigned short* w2t = (unsigned short*)p;  p += (size_t)NL * 4 * DMODEL * DMODEL * 2;
  unsigned short* woutt = (unsigned short*)p; p += (size_t)VOCAB * DMODEL * 2;

  transconv<<<dim3(32, 16, NL), 256, 0, stream>>>(Wo, wot, DMODEL, DMODEL);
  transconv<<<dim3(128, 16, NL), 256, 0, stream>>>(W1, w1t, DMODEL, 4 * DMODEL);
  transconv<<<dim3(32, 64, NL), 256, 0, stream>>>(W2, w2t, 4 * DMODEL, DMODEL);
  transconv<<<dim3(1000, 16, 1), 256, 0, stream>>>(W_out, woutt, DMODEL, VOCAB);
  qkv_transconv<<<dim3(2, 16, NL * 48), 256, 0, stream>>>(Wq, Wk, Wv, qkvt);

  embed_kernel<<<ROWS, 256, 0, stream>>>(tokens, tok_emb, pos_emb, x);

  for (int l = 0; l < NL; ++l) {
    ln_kernel<<<ROWS, 256, 0, stream>>>(x, hb, ln1_g + l * DMODEL, ln1_b + l * DMODEL);
    mmP<EPI_QKV><<<768, 256, 0, stream>>>(
        hb, qkvt + (size_t)l * 3 * DMODEL * DMODEL, nullptr, nullptr,
        nullptr, qb, kb, vtb, ROWS, 3 * DMODEL, DMODEL);
    attn_mfma<<<dim3(SEQ / 128, NB * NH), 512, 0, stream>>>(qb, kb, vtb, att);
    mmP<EPI_RES><<<256, 256, 0, stream>>>(
        att, wot + (size_t)l * DMODEL * DMODEL, bo + l * DMODEL, x,
        x, nullptr, nullptr, nullptr, ROWS, DMODEL, DMODEL);
    ln_kernel<<<ROWS, 256, 0, stream>>>(x, hb, ln2_g + l * DMODEL, ln2_b + l * DMODEL);
    mmP<EPI_RELU><<<1024, 256, 0, stream>>>(
        hb, w1t + (size_t)l * 4 * DMODEL * DMODEL, b1 + (size_t)l * 4 * DMODEL, nullptr,
        nullptr, hid, nullptr, nullptr, ROWS, 4 * DMODEL, DMODEL);
    mmP<EPI_RES><<<256, 256, 0, stream>>>(
        hid, w2t + (size_t)l * 4 * DMODEL * DMODEL, b2 + l * DMODEL, x,
        x, nullptr, nullptr, nullptr, ROWS, DMODEL, 4 * DMODEL);
  }

  ln_kernel<<<ROWS, 256, 0, stream>>>(x, hb, lnf_g, lnf_b);
  mmX<EPI_LOGITS, 256, 1><<<2000, 512, 0, stream>>>(
      hb, woutt, b_out, nullptr, logits, nullptr, nullptr, nullptr,
      ROWS, VOCAB, DMODEL);
}